// Round 5
// baseline (344.966 us; speedup 1.0000x reference)
//
#include <hip/hip_runtime.h>
#include <math.h>

#define Kk 8
#define Bb 32
#define Cc 3
#define HW 36864          // 192*192
#define CHW 110592        // 3*HW
#define BCHW 3538944      // B*C*HW
#define OUTMAIN 31850496  // 9*BCHW : start of index tail in d_out (elements)
#define INVVAR 11.11111111111111f
#define EPSf 1e-5f

__device__ __forceinline__ int clampK(int v) { return v < 0 ? 0 : (v > Kk - 1 ? Kk - 1 : v); }

// ---------------------------------------------------------------------------
// k_pre: recon -> out[0].  Scalar loads, coalesced (thread-stride 256).
// grid: 32*36 = 1152 blocks x 256 threads, 4 px/thread.
// ---------------------------------------------------------------------------
__global__ __launch_bounds__(256) void k_pre(
    const float* __restrict__ apc, const float* __restrict__ shp,
    const float* __restrict__ zeta, const float* __restrict__ back,
    float* __restrict__ out)
{
    int b = blockIdx.x / 36, ch = blockIdx.x % 36;
    int tid = threadIdx.x;
    float zl[Kk];
#pragma unroll
    for (int k = 0; k < Kk; ++k) zl[k] = zeta[k * Bb + b];
    for (int p = 0; p < 4; ++p) {
        int pix = ch * 1024 + p * 256 + tid;
        float cum = 1.f, r0 = 0.f, r1 = 0.f, r2 = 0.f;
#pragma unroll
        for (int k = 0; k < Kk; ++k) {
            float s = shp[(size_t)(k * Bb + b) * HW + pix];
            float x = s * zl[k];
            float g = x * cum;
            r0 += g * apc[((size_t)(k * Bb + b) * Cc + 0) * HW + pix];
            r1 += g * apc[((size_t)(k * Bb + b) * Cc + 1) * HW + pix];
            r2 += g * apc[((size_t)(k * Bb + b) * Cc + 2) * HW + pix];
            cum *= (1.f - x);
        }
        out[(size_t)(b * Cc + 0) * HW + pix] = r0 + cum * back[(size_t)(b * Cc + 0) * HW + pix];
        out[(size_t)(b * Cc + 1) * HW + pix] = r1 + cum * back[(size_t)(b * Cc + 1) * HW + pix];
        out[(size_t)(b * Cc + 2) * HW + pix] = r2 + cum * back[(size_t)(b * Cc + 2) * HW + pix];
    }
}

// ---------------------------------------------------------------------------
// k_red (step t): recompute P from idx history + diffs from apc/images,
// reduce {sum sd*P, sum shp*P, max shp*P} per (k,b).  LDS tree, no shuffles.
// grid: 1152 blocks x 256 threads, 4 px/thread. partials: [b][24][36]
// ---------------------------------------------------------------------------
__global__ __launch_bounds__(256) void k_red(
    const float* __restrict__ images, const float* __restrict__ apc,
    const float* __restrict__ shp, const float* __restrict__ idxf,
    float* __restrict__ partials, int t)
{
    int b = blockIdx.x / 36, ch = blockIdx.x % 36;
    int tid = threadIdx.x;
    int hist[Kk];
    for (int j = 0; j < t; ++j) hist[j] = clampK((int)idxf[j * Bb + b]);

    float acc[24];
#pragma unroll
    for (int q = 0; q < 24; ++q) acc[q] = (q % 3 == 2) ? -1e30f : 0.f;

    for (int p = 0; p < 4; ++p) {
        int pix = ch * 1024 + p * 256 + tid;
        float i0 = images[(size_t)(b * Cc + 0) * HW + pix];
        float i1 = images[(size_t)(b * Cc + 1) * HW + pix];
        float i2 = images[(size_t)(b * Cc + 2) * HW + pix];
        float P = 1.f;
        for (int j = 0; j < t; ++j) {
            float sh = shp[(size_t)(hist[j] * Bb + b) * HW + pix];
            P *= (1.f - sh * P);
        }
#pragma unroll
        for (int k = 0; k < Kk; ++k) {
            float s  = shp[(size_t)(k * Bb + b) * HW + pix];
            float d0 = apc[((size_t)(k * Bb + b) * Cc + 0) * HW + pix] - i0;
            float d1 = apc[((size_t)(k * Bb + b) * Cc + 1) * HW + pix] - i1;
            float d2 = apc[((size_t)(k * Bb + b) * Cc + 2) * HW + pix] - i2;
            float df = d0 * d0 + d1 * d1 + d2 * d2;
            float m = s * P;
            acc[3 * k + 0] += s * df * P;
            acc[3 * k + 1] += m;
            acc[3 * k + 2] = fmaxf(acc[3 * k + 2], m);
        }
    }

    __shared__ float ls[256][25];
#pragma unroll
    for (int q = 0; q < 24; ++q) ls[tid][q] = acc[q];
    __syncthreads();
    for (int st = 128; st > 0; st >>= 1) {
        if (tid < st) {
#pragma unroll
            for (int q = 0; q < 24; ++q) {
                float o = ls[tid + st][q];
                ls[tid][q] = (q % 3 == 2) ? fmaxf(ls[tid][q], o) : (ls[tid][q] + o);
            }
        }
        __syncthreads();
    }
    if (tid < 24) partials[(size_t)b * 864 + tid * 36 + ch] = ls[0][tid];
}

// ---------------------------------------------------------------------------
// k_score (step t): final reduce over 36 chunks, scores, argmax -> idxf[t]
// grid: 32 blocks x 64 threads
// ---------------------------------------------------------------------------
__global__ __launch_bounds__(64) void k_score(
    const float* __restrict__ partials, const float* __restrict__ zeta,
    float* idxf, int t)
{
    int b = blockIdx.x, tid = threadIdx.x;
    __shared__ float vals[24];
    if (tid < 24) {
        int comp = tid % 3;
        float v = (comp == 2) ? -1e30f : 0.f;
        for (int j = 0; j < 36; ++j) {
            float x = partials[(size_t)b * 864 + tid * 36 + j];
            v = (comp == 2) ? fmaxf(v, x) : (v + x);
        }
        vals[tid] = v;
    }
    __syncthreads();
    if (tid == 0) {
        float best = -1e30f; int bi = 0;
        for (int k = 0; k < Kk; ++k) {
            float coef = 1.f;
            for (int j = 0; j < t; ++j)
                if (clampK((int)idxf[j * Bb + b]) == k) coef = -1.f;
            float sc = coef * vals[3 * k + 2] * zeta[k * Bb + b] *
                       expf(-0.5f * INVVAR * vals[3 * k + 0] / (vals[3 * k + 1] + EPSf));
            if (sc > best) { best = sc; bi = k; }
        }
        idxf[t * Bb + b] = (float)bi;
    }
}

// ---------------------------------------------------------------------------
// k_gather: out[1+t] = apc[idx[t]].  Scalar copy; each block stays inside one
// (t,b) image (CHW = 108*1024 exactly).  grid: 256*108 = 27648 blocks.
// ---------------------------------------------------------------------------
__global__ __launch_bounds__(256) void k_gather(
    const float* __restrict__ apc, const float* __restrict__ idxf,
    float* __restrict__ out)
{
    int image = blockIdx.x / 108;          // 0..255 == t*32+b
    int chunk = blockIdx.x % 108;
    int t = image >> 5, b = image & 31;
    int s = clampK((int)idxf[t * Bb + b]);
    size_t src0 = (size_t)(s * Bb + b) * CHW;
    size_t dst0 = (size_t)(image + Bb) * CHW;   // ((1+t)*32+b)*CHW
    for (int p = 0; p < 4; ++p) {
        int off = chunk * 1024 + p * 256 + threadIdx.x;
        out[dst0 + off] = apc[src0 + off];
    }
}

// ---------------------------------------------------------------------------
// Conservative round: f32 everywhere (npz sizes say f32), scalar accesses only,
// no shuffles, no big scratch. Only cross-kernel state: partials (110KB, in
// d_ws if available else inside out[1..8]) and the 256-element index tail.
// ---------------------------------------------------------------------------
extern "C" void kernel_launch(void* const* d_in, const int* in_sizes, int n_in,
                              void* d_out, int out_size, void* d_ws, size_t ws_size,
                              hipStream_t stream)
{
    const float *images = nullptr, *apc = nullptr, *shp = nullptr;
    const float *zeta = nullptr, *back = nullptr;
    for (int i = 0; i < n_in; ++i) {
        int s = in_sizes[i];
        if (s == 28311552)      apc  = (const float*)d_in[i];
        else if (s == 9437184)  shp  = (const float*)d_in[i];
        else if (s == 256)      zeta = (const float*)d_in[i];
        else if (s == 3538944) {
            if (!images) images = (const float*)d_in[i];
            else         back   = (const float*)d_in[i];
        }
    }
    if (!images || !apc || !shp || !zeta || !back) {   // fallback: dict order
        images = (const float*)d_in[0]; apc = (const float*)d_in[1];
        shp = (const float*)d_in[2]; zeta = (const float*)d_in[3];
        back = (const float*)d_in[4];
    }
    float* out = (float*)d_out;
    float* idxf = out + OUTMAIN;                       // 256-element tail

    // partials: 32*864 floats = 110,592 B
    float* partials = (d_ws != nullptr && ws_size >= 262144)
                        ? (float*)d_ws
                        : (out + 4194304);             // inside out[1..8], dead before gather

    k_pre<<<1152, 256, 0, stream>>>(apc, shp, zeta, back, out);
    for (int t = 0; t < Kk; ++t) {
        k_red<<<1152, 256, 0, stream>>>(images, apc, shp, idxf, partials, t);
        k_score<<<32, 64, 0, stream>>>(partials, zeta, idxf, t);
    }
    k_gather<<<27648, 256, 0, stream>>>(apc, idxf, out);
}

// Round 6
// 275.103 us; speedup vs baseline: 1.2540x; 1.2540x over previous
//
#include <hip/hip_runtime.h>
#include <math.h>

#define Kk 8
#define Bb 32
#define Cc 3
#define HW 36864          // 192*192
#define CHW 110592        // 3*HW
#define BCHW 3538944      // B*C*HW
#define OUTMAIN 31850496  // 9*BCHW : start of index tail in d_out (elements)
#define INVVAR 11.11111111111111f
#define EPSf 1e-5f

__device__ __forceinline__ int clampK(int v) { return v < 0 ? 0 : (v > Kk - 1 ? Kk - 1 : v); }

// ---------------------------------------------------------------------------
// FAST PATH kernel 1: recon -> out[0]  AND  sd = shp * sum_c (apc-img)^2.
// Scalar loads, coalesced. grid: 32*36 = 1152 blocks x 256 threads, 4 px/thr.
// ---------------------------------------------------------------------------
__global__ __launch_bounds__(256) void k_pre_fused(
    const float* __restrict__ images, const float* __restrict__ apc,
    const float* __restrict__ shp, const float* __restrict__ zeta,
    const float* __restrict__ back, float* __restrict__ out,
    float* __restrict__ sd)
{
    int b = blockIdx.x / 36, ch = blockIdx.x % 36;
    int tid = threadIdx.x;
    float zl[Kk];
#pragma unroll
    for (int k = 0; k < Kk; ++k) zl[k] = zeta[k * Bb + b];
    for (int p = 0; p < 4; ++p) {
        int pix = ch * 1024 + p * 256 + tid;
        float i0 = images[(size_t)(b * Cc + 0) * HW + pix];
        float i1 = images[(size_t)(b * Cc + 1) * HW + pix];
        float i2 = images[(size_t)(b * Cc + 2) * HW + pix];
        float cum = 1.f, r0 = 0.f, r1 = 0.f, r2 = 0.f;
#pragma unroll
        for (int k = 0; k < Kk; ++k) {
            float s = shp[(size_t)(k * Bb + b) * HW + pix];
            float a0 = apc[((size_t)(k * Bb + b) * Cc + 0) * HW + pix];
            float a1 = apc[((size_t)(k * Bb + b) * Cc + 1) * HW + pix];
            float a2 = apc[((size_t)(k * Bb + b) * Cc + 2) * HW + pix];
            float x = s * zl[k];
            float g = x * cum;
            r0 += g * a0; r1 += g * a1; r2 += g * a2;
            float d0 = a0 - i0, d1 = a1 - i1, d2 = a2 - i2;
            sd[(size_t)(k * Bb + b) * HW + pix] = s * (d0 * d0 + d1 * d1 + d2 * d2);
            cum *= (1.f - x);
        }
        out[(size_t)(b * Cc + 0) * HW + pix] = r0 + cum * back[(size_t)(b * Cc + 0) * HW + pix];
        out[(size_t)(b * Cc + 1) * HW + pix] = r1 + cum * back[(size_t)(b * Cc + 1) * HW + pix];
        out[(size_t)(b * Cc + 2) * HW + pix] = r2 + cum * back[(size_t)(b * Cc + 2) * HW + pix];
    }
}

// ---------------------------------------------------------------------------
// FAST PATH kernel 2 (step t): update persistent P, reduce
// {sum sd*P, sum shp*P, max shp*P} per (k,b).  LDS tree, scalar loads.
// grid: 1152 blocks x 256 threads, 4 px/thread. partials: [b][24][36]
// ---------------------------------------------------------------------------
__global__ __launch_bounds__(256) void k_red_fast(
    const float* __restrict__ shp, const float* __restrict__ sd,
    float* __restrict__ Pbuf, const float* __restrict__ idxf,
    float* __restrict__ partials, int t)
{
    int b = blockIdx.x / 36, ch = blockIdx.x % 36;
    int tid = threadIdx.x;
    int sel = (t > 0) ? clampK((int)idxf[(t - 1) * Bb + b]) : 0;

    float acc[24];
#pragma unroll
    for (int q = 0; q < 24; ++q) acc[q] = (q % 3 == 2) ? -1e30f : 0.f;

    for (int p = 0; p < 4; ++p) {
        int pix = ch * 1024 + p * 256 + tid;
        float P;
        if (t == 0) {
            P = 1.f;
        } else {
            float prev = (t == 1) ? 1.f : Pbuf[(size_t)b * HW + pix];
            float sh = shp[(size_t)(sel * Bb + b) * HW + pix];
            P = prev * (1.f - sh * prev);
            Pbuf[(size_t)b * HW + pix] = P;
        }
#pragma unroll
        for (int k = 0; k < Kk; ++k) {
            float s = shp[(size_t)(k * Bb + b) * HW + pix];
            float v = sd [(size_t)(k * Bb + b) * HW + pix];
            float m = s * P;
            acc[3 * k + 0] += v * P;
            acc[3 * k + 1] += m;
            acc[3 * k + 2] = fmaxf(acc[3 * k + 2], m);
        }
    }

    __shared__ float ls[256][25];
#pragma unroll
    for (int q = 0; q < 24; ++q) ls[tid][q] = acc[q];
    __syncthreads();
    for (int st = 128; st > 0; st >>= 1) {
        if (tid < st) {
#pragma unroll
            for (int q = 0; q < 24; ++q) {
                float o = ls[tid + st][q];
                ls[tid][q] = (q % 3 == 2) ? fmaxf(ls[tid][q], o) : (ls[tid][q] + o);
            }
        }
        __syncthreads();
    }
    if (tid < 24) partials[(size_t)b * 864 + tid * 36 + ch] = ls[0][tid];
}

// ---------------------------------------------------------------------------
// FALLBACK kernel 1 (round-5): recon only
// ---------------------------------------------------------------------------
__global__ __launch_bounds__(256) void k_pre(
    const float* __restrict__ apc, const float* __restrict__ shp,
    const float* __restrict__ zeta, const float* __restrict__ back,
    float* __restrict__ out)
{
    int b = blockIdx.x / 36, ch = blockIdx.x % 36;
    int tid = threadIdx.x;
    float zl[Kk];
#pragma unroll
    for (int k = 0; k < Kk; ++k) zl[k] = zeta[k * Bb + b];
    for (int p = 0; p < 4; ++p) {
        int pix = ch * 1024 + p * 256 + tid;
        float cum = 1.f, r0 = 0.f, r1 = 0.f, r2 = 0.f;
#pragma unroll
        for (int k = 0; k < Kk; ++k) {
            float s = shp[(size_t)(k * Bb + b) * HW + pix];
            float x = s * zl[k];
            float g = x * cum;
            r0 += g * apc[((size_t)(k * Bb + b) * Cc + 0) * HW + pix];
            r1 += g * apc[((size_t)(k * Bb + b) * Cc + 1) * HW + pix];
            r2 += g * apc[((size_t)(k * Bb + b) * Cc + 2) * HW + pix];
            cum *= (1.f - x);
        }
        out[(size_t)(b * Cc + 0) * HW + pix] = r0 + cum * back[(size_t)(b * Cc + 0) * HW + pix];
        out[(size_t)(b * Cc + 1) * HW + pix] = r1 + cum * back[(size_t)(b * Cc + 1) * HW + pix];
        out[(size_t)(b * Cc + 2) * HW + pix] = r2 + cum * back[(size_t)(b * Cc + 2) * HW + pix];
    }
}

// ---------------------------------------------------------------------------
// FALLBACK kernel 2 (round-5): recompute P + diffs from inputs each step
// ---------------------------------------------------------------------------
__global__ __launch_bounds__(256) void k_red(
    const float* __restrict__ images, const float* __restrict__ apc,
    const float* __restrict__ shp, const float* __restrict__ idxf,
    float* __restrict__ partials, int t)
{
    int b = blockIdx.x / 36, ch = blockIdx.x % 36;
    int tid = threadIdx.x;
    int hist[Kk];
    for (int j = 0; j < t; ++j) hist[j] = clampK((int)idxf[j * Bb + b]);

    float acc[24];
#pragma unroll
    for (int q = 0; q < 24; ++q) acc[q] = (q % 3 == 2) ? -1e30f : 0.f;

    for (int p = 0; p < 4; ++p) {
        int pix = ch * 1024 + p * 256 + tid;
        float i0 = images[(size_t)(b * Cc + 0) * HW + pix];
        float i1 = images[(size_t)(b * Cc + 1) * HW + pix];
        float i2 = images[(size_t)(b * Cc + 2) * HW + pix];
        float P = 1.f;
        for (int j = 0; j < t; ++j) {
            float sh = shp[(size_t)(hist[j] * Bb + b) * HW + pix];
            P *= (1.f - sh * P);
        }
#pragma unroll
        for (int k = 0; k < Kk; ++k) {
            float s  = shp[(size_t)(k * Bb + b) * HW + pix];
            float d0 = apc[((size_t)(k * Bb + b) * Cc + 0) * HW + pix] - i0;
            float d1 = apc[((size_t)(k * Bb + b) * Cc + 1) * HW + pix] - i1;
            float d2 = apc[((size_t)(k * Bb + b) * Cc + 2) * HW + pix] - i2;
            float df = d0 * d0 + d1 * d1 + d2 * d2;
            float m = s * P;
            acc[3 * k + 0] += s * df * P;
            acc[3 * k + 1] += m;
            acc[3 * k + 2] = fmaxf(acc[3 * k + 2], m);
        }
    }

    __shared__ float ls[256][25];
#pragma unroll
    for (int q = 0; q < 24; ++q) ls[tid][q] = acc[q];
    __syncthreads();
    for (int st = 128; st > 0; st >>= 1) {
        if (tid < st) {
#pragma unroll
            for (int q = 0; q < 24; ++q) {
                float o = ls[tid + st][q];
                ls[tid][q] = (q % 3 == 2) ? fmaxf(ls[tid][q], o) : (ls[tid][q] + o);
            }
        }
        __syncthreads();
    }
    if (tid < 24) partials[(size_t)b * 864 + tid * 36 + ch] = ls[0][tid];
}

// ---------------------------------------------------------------------------
// k_score (step t): final reduce over 36 chunks, scores, argmax -> idxf[t]
// grid: 32 blocks x 64 threads
// ---------------------------------------------------------------------------
__global__ __launch_bounds__(64) void k_score(
    const float* __restrict__ partials, const float* __restrict__ zeta,
    float* idxf, int t)
{
    int b = blockIdx.x, tid = threadIdx.x;
    __shared__ float vals[24];
    if (tid < 24) {
        int comp = tid % 3;
        float v = (comp == 2) ? -1e30f : 0.f;
        for (int j = 0; j < 36; ++j) {
            float x = partials[(size_t)b * 864 + tid * 36 + j];
            v = (comp == 2) ? fmaxf(v, x) : (v + x);
        }
        vals[tid] = v;
    }
    __syncthreads();
    if (tid == 0) {
        float best = -1e30f; int bi = 0;
        for (int k = 0; k < Kk; ++k) {
            float coef = 1.f;
            for (int j = 0; j < t; ++j)
                if (clampK((int)idxf[j * Bb + b]) == k) coef = -1.f;
            float sc = coef * vals[3 * k + 2] * zeta[k * Bb + b] *
                       expf(-0.5f * INVVAR * vals[3 * k + 0] / (vals[3 * k + 1] + EPSf));
            if (sc > best) { best = sc; bi = k; }
        }
        idxf[t * Bb + b] = (float)bi;
    }
}

// ---------------------------------------------------------------------------
// k_gather: out[1+t] = apc[idx[t]].  Scalar copy; each block inside one image.
// grid: 256*108 = 27648 blocks.
// ---------------------------------------------------------------------------
__global__ __launch_bounds__(256) void k_gather(
    const float* __restrict__ apc, const float* __restrict__ idxf,
    float* __restrict__ out)
{
    int image = blockIdx.x / 108;          // 0..255 == t*32+b
    int chunk = blockIdx.x % 108;
    int t = image >> 5, b = image & 31;
    int s = clampK((int)idxf[t * Bb + b]);
    size_t src0 = (size_t)(s * Bb + b) * CHW;
    size_t dst0 = (size_t)(image + Bb) * CHW;   // ((1+t)*32+b)*CHW
    for (int p = 0; p < 4; ++p) {
        int off = chunk * 1024 + p * 256 + threadIdx.x;
        out[dst0 + off] = apc[src0 + off];
    }
}

// ---------------------------------------------------------------------------
// FAST PATH (ws_size >= 48MB): precompute sd once, carry P in d_ws -> each
// step reads shp+sd+P (~85MB, L2/L3-resident) instead of recomputing from
// apc (165MB logical). FALLBACK: exact round-5 structure (proven passing).
// All scratch is fully rewritten before use every call -> deterministic.
// ---------------------------------------------------------------------------
extern "C" void kernel_launch(void* const* d_in, const int* in_sizes, int n_in,
                              void* d_out, int out_size, void* d_ws, size_t ws_size,
                              hipStream_t stream)
{
    const float *images = nullptr, *apc = nullptr, *shp = nullptr;
    const float *zeta = nullptr, *back = nullptr;
    for (int i = 0; i < n_in; ++i) {
        int s = in_sizes[i];
        if (s == 28311552)      apc  = (const float*)d_in[i];
        else if (s == 9437184)  shp  = (const float*)d_in[i];
        else if (s == 256)      zeta = (const float*)d_in[i];
        else if (s == 3538944) {
            if (!images) images = (const float*)d_in[i];
            else         back   = (const float*)d_in[i];
        }
    }
    if (!images || !apc || !shp || !zeta || !back) {   // fallback: dict order
        images = (const float*)d_in[0]; apc = (const float*)d_in[1];
        shp = (const float*)d_in[2]; zeta = (const float*)d_in[3];
        back = (const float*)d_in[4];
    }
    float* out = (float*)d_out;
    float* idxf = out + OUTMAIN;                       // 256-element tail

    if (d_ws != nullptr && ws_size >= (size_t)48 * 1024 * 1024) {
        float* sd       = (float*)d_ws;                // 9,437,184 f32
        float* Pbuf     = sd + 9437184;                // 1,179,648 f32
        float* partials = Pbuf + 1179648;              // 27,648 f32
        k_pre_fused<<<1152, 256, 0, stream>>>(images, apc, shp, zeta, back, out, sd);
        for (int t = 0; t < Kk; ++t) {
            k_red_fast<<<1152, 256, 0, stream>>>(shp, sd, Pbuf, idxf, partials, t);
            k_score<<<32, 64, 0, stream>>>(partials, zeta, idxf, t);
        }
        k_gather<<<27648, 256, 0, stream>>>(apc, idxf, out);
    } else {
        float* partials = (d_ws != nullptr && ws_size >= 262144)
                            ? (float*)d_ws
                            : (out + 4194304);
        k_pre<<<1152, 256, 0, stream>>>(apc, shp, zeta, back, out);
        for (int t = 0; t < Kk; ++t) {
            k_red<<<1152, 256, 0, stream>>>(images, apc, shp, idxf, partials, t);
            k_score<<<32, 64, 0, stream>>>(partials, zeta, idxf, t);
        }
        k_gather<<<27648, 256, 0, stream>>>(apc, idxf, out);
    }
}

// Round 7
// 259.584 us; speedup vs baseline: 1.3289x; 1.0598x over previous
//
#include <hip/hip_runtime.h>
#include <math.h>

#define Kk 8
#define Bb 32
#define Cc 3
#define HW 36864          // 192*192
#define HW4 9216          // HW/4 (float4s per image plane)
#define CHW 110592        // 3*HW
#define CHW4 27648        // CHW/4
#define BCHW 3538944      // B*C*HW
#define OUTMAIN 31850496  // 9*BCHW : start of index tail in d_out (elements)
#define INVVAR 11.11111111111111f
#define EPSf 1e-5f

__device__ __forceinline__ int clampK(int v) { return v < 0 ? 0 : (v > Kk - 1 ? Kk - 1 : v); }
__device__ __forceinline__ float4 ld4(const float* p) { return *reinterpret_cast<const float4*>(p); }
__device__ __forceinline__ void st4(float* p, float4 v) { *reinterpret_cast<float4*>(p) = v; }

// ---------------------------------------------------------------------------
// Kernel 1: recon -> out[0]  AND  sd = shp * sum_c (apc-img)^2.
// float4 loads/stores, 1 float4 per thread. grid: B*HW4/256 = 1152 x 256.
// ---------------------------------------------------------------------------
__global__ __launch_bounds__(256) void k_pre_fused(
    const float* __restrict__ images, const float* __restrict__ apc,
    const float* __restrict__ shp, const float* __restrict__ zeta,
    const float* __restrict__ back, float* __restrict__ out,
    float* __restrict__ sd)
{
    int gid = blockIdx.x * 256 + threadIdx.x;     // float4 id over B*HW4
    int b = gid / HW4;
    int pix = (gid - b * HW4) * 4;

    float4 img[Cc], bk[Cc], rec[Cc];
#pragma unroll
    for (int c = 0; c < Cc; ++c) {
        img[c] = ld4(images + (size_t)(b * Cc + c) * HW + pix);
        bk[c]  = ld4(back   + (size_t)(b * Cc + c) * HW + pix);
        rec[c] = make_float4(0.f, 0.f, 0.f, 0.f);
    }
    float cum0 = 1.f, cum1 = 1.f, cum2 = 1.f, cum3 = 1.f;

#pragma unroll
    for (int k = 0; k < Kk; ++k) {
        float4 s = ld4(shp + (size_t)(k * Bb + b) * HW + pix);
        float z = zeta[k * Bb + b];
        float x0 = s.x * z, x1 = s.y * z, x2 = s.z * z, x3 = s.w * z;
        float g0 = x0 * cum0, g1 = x1 * cum1, g2 = x2 * cum2, g3 = x3 * cum3;
        float df0 = 0.f, df1 = 0.f, df2 = 0.f, df3 = 0.f;
#pragma unroll
        for (int c = 0; c < Cc; ++c) {
            float4 a = ld4(apc + ((size_t)(k * Bb + b) * Cc + c) * HW + pix);
            float d0 = a.x - img[c].x, d1 = a.y - img[c].y;
            float d2 = a.z - img[c].z, d3 = a.w - img[c].w;
            df0 += d0 * d0; df1 += d1 * d1; df2 += d2 * d2; df3 += d3 * d3;
            rec[c].x += g0 * a.x; rec[c].y += g1 * a.y;
            rec[c].z += g2 * a.z; rec[c].w += g3 * a.w;
        }
        st4(sd + (size_t)(k * Bb + b) * HW + pix,
            make_float4(s.x * df0, s.y * df1, s.z * df2, s.w * df3));
        cum0 *= (1.f - x0); cum1 *= (1.f - x1); cum2 *= (1.f - x2); cum3 *= (1.f - x3);
    }
#pragma unroll
    for (int c = 0; c < Cc; ++c) {
        st4(out + (size_t)(b * Cc + c) * HW + pix,
            make_float4(rec[c].x + cum0 * bk[c].x, rec[c].y + cum1 * bk[c].y,
                        rec[c].z + cum2 * bk[c].z, rec[c].w + cum3 * bk[c].w));
    }
}

// ---------------------------------------------------------------------------
// Kernel 2 (step t): update persistent P, reduce {sum sd*P, sum shp*P,
// max shp*P} per (k,b). float4 loads, LDS tree (NO shuffles).
// grid: 1152 x 256, thread = 1 float4 (pix = ch*1024 + tid*4).
// LDS folded st=128 level -> 12.8KB (bit-identical pairing to round 6).
// partials: [b][24][36]
// ---------------------------------------------------------------------------
__global__ __launch_bounds__(256) void k_red_fast(
    const float* __restrict__ shp, const float* __restrict__ sd,
    float* __restrict__ Pbuf, const float* __restrict__ idxf,
    float* __restrict__ partials, int t)
{
    int b = blockIdx.x / 36, ch = blockIdx.x % 36;
    int tid = threadIdx.x;
    int pix = ch * 1024 + tid * 4;
    int sel = (t > 0) ? clampK((int)idxf[(t - 1) * Bb + b]) : 0;

    float P0, P1, P2, P3;
    if (t == 0) {
        P0 = P1 = P2 = P3 = 1.f;
    } else {
        float pr0 = 1.f, pr1 = 1.f, pr2 = 1.f, pr3 = 1.f;
        if (t > 1) {
            float4 p4 = ld4(Pbuf + (size_t)b * HW + pix);
            pr0 = p4.x; pr1 = p4.y; pr2 = p4.z; pr3 = p4.w;
        }
        float4 sh = ld4(shp + (size_t)(sel * Bb + b) * HW + pix);
        P0 = pr0 * (1.f - sh.x * pr0); P1 = pr1 * (1.f - sh.y * pr1);
        P2 = pr2 * (1.f - sh.z * pr2); P3 = pr3 * (1.f - sh.w * pr3);
        st4(Pbuf + (size_t)b * HW + pix, make_float4(P0, P1, P2, P3));
    }

    float acc[24];
#pragma unroll
    for (int k = 0; k < Kk; ++k) {
        float4 s = ld4(shp + (size_t)(k * Bb + b) * HW + pix);
        float4 v = ld4(sd  + (size_t)(k * Bb + b) * HW + pix);
        float m0 = s.x * P0, m1 = s.y * P1, m2 = s.z * P2, m3 = s.w * P3;
        acc[3 * k + 0] = (v.x * P0 + v.y * P1) + (v.z * P2 + v.w * P3);
        acc[3 * k + 1] = (m0 + m1) + (m2 + m3);
        acc[3 * k + 2] = fmaxf(fmaxf(m0, m1), fmaxf(m2, m3));
    }

    __shared__ float ls[128][25];
    if (tid >= 128) {
#pragma unroll
        for (int q = 0; q < 24; ++q) ls[tid - 128][q] = acc[q];
    }
    __syncthreads();
    if (tid < 128) {
#pragma unroll
        for (int q = 0; q < 24; ++q) {
            float o = ls[tid][q];
            ls[tid][q] = (q % 3 == 2) ? fmaxf(acc[q], o) : (acc[q] + o);
        }
    }
    __syncthreads();
    for (int st = 64; st > 0; st >>= 1) {
        if (tid < st) {
#pragma unroll
            for (int q = 0; q < 24; ++q) {
                float o = ls[tid + st][q];
                ls[tid][q] = (q % 3 == 2) ? fmaxf(ls[tid][q], o) : (ls[tid][q] + o);
            }
        }
        __syncthreads();
    }
    if (tid < 24) partials[(size_t)b * 864 + tid * 36 + ch] = ls[0][tid];
}

// ---------------------------------------------------------------------------
// Kernel 3 (step t): final reduce over 36 chunks, scores, argmax -> idxf[t]
// grid: 32 x 64
// ---------------------------------------------------------------------------
__global__ __launch_bounds__(64) void k_score(
    const float* __restrict__ partials, const float* __restrict__ zeta,
    float* idxf, int t)
{
    int b = blockIdx.x, tid = threadIdx.x;
    __shared__ float vals[24];
    if (tid < 24) {
        int comp = tid % 3;
        float v = (comp == 2) ? -1e30f : 0.f;
        for (int j = 0; j < 36; ++j) {
            float x = partials[(size_t)b * 864 + tid * 36 + j];
            v = (comp == 2) ? fmaxf(v, x) : (v + x);
        }
        vals[tid] = v;
    }
    __syncthreads();
    if (tid == 0) {
        float best = -1e30f; int bi = 0;
        for (int k = 0; k < Kk; ++k) {
            float coef = 1.f;
            for (int j = 0; j < t; ++j)
                if (clampK((int)idxf[j * Bb + b]) == k) coef = -1.f;
            float sc = coef * vals[3 * k + 2] * zeta[k * Bb + b] *
                       expf(-0.5f * INVVAR * vals[3 * k + 0] / (vals[3 * k + 1] + EPSf));
            if (sc > best) { best = sc; bi = k; }
        }
        idxf[t * Bb + b] = (float)bi;
    }
}

// ---------------------------------------------------------------------------
// Kernel 4: out[1+t] = apc[idx[t]]  (float4 copy). grid: 27648 x 256.
// ---------------------------------------------------------------------------
__global__ __launch_bounds__(256) void k_gather(
    const float* __restrict__ apc, const float* __restrict__ idxf,
    float* __restrict__ out)
{
    int g = blockIdx.x * 256 + threadIdx.x;   // float4 id over K*B*CHW4
    int tb = g / CHW4;
    int off = g - tb * CHW4;
    int t = tb >> 5, b = tb & 31;
    int s = clampK((int)idxf[t * Bb + b]);
    const float4* src = reinterpret_cast<const float4*>(apc) + (size_t)(s * Bb + b) * CHW4 + off;
    float4* dst = reinterpret_cast<float4*>(out) + (size_t)((1 + t) * Bb + b) * CHW4 + off;
    *dst = *src;
}

// ---------------------------------------------------------------------------
// Controlled experiment vs round 6 (passed, 275us): float4 loads re-introduced
// everywhere; LDS-tree reduction kept (no shuffles); d_ws scratch kept.
// If this aborts -> vector memory ops are the rounds-1..4 crasher; else they
// were innocent (shuffles condemned) and vectorization stands.
// ---------------------------------------------------------------------------
extern "C" void kernel_launch(void* const* d_in, const int* in_sizes, int n_in,
                              void* d_out, int out_size, void* d_ws, size_t ws_size,
                              hipStream_t stream)
{
    const float *images = nullptr, *apc = nullptr, *shp = nullptr;
    const float *zeta = nullptr, *back = nullptr;
    for (int i = 0; i < n_in; ++i) {
        int s = in_sizes[i];
        if (s == 28311552)      apc  = (const float*)d_in[i];
        else if (s == 9437184)  shp  = (const float*)d_in[i];
        else if (s == 256)      zeta = (const float*)d_in[i];
        else if (s == 3538944) {
            if (!images) images = (const float*)d_in[i];
            else         back   = (const float*)d_in[i];
        }
    }
    if (!images || !apc || !shp || !zeta || !back) {   // fallback: dict order
        images = (const float*)d_in[0]; apc = (const float*)d_in[1];
        shp = (const float*)d_in[2]; zeta = (const float*)d_in[3];
        back = (const float*)d_in[4];
    }
    float* out = (float*)d_out;
    float* idxf = out + OUTMAIN;                       // 256-element tail

    // Scratch: prefer d_ws (proven working, needs 42.6MB); else alias into
    // out[1..8] (dead before k_gather rewrites it).
    float *sd, *Pbuf, *partials;
    if (d_ws != nullptr && ws_size >= (size_t)48 * 1024 * 1024) {
        sd = (float*)d_ws;
    } else {
        sd = out + BCHW;
    }
    Pbuf     = sd + 9437184;
    partials = Pbuf + 1179648;

    k_pre_fused<<<1152, 256, 0, stream>>>(images, apc, shp, zeta, back, out, sd);
    for (int t = 0; t < Kk; ++t) {
        k_red_fast<<<1152, 256, 0, stream>>>(shp, sd, Pbuf, idxf, partials, t);
        k_score<<<32, 64, 0, stream>>>(partials, zeta, idxf, t);
    }
    k_gather<<<27648, 256, 0, stream>>>(apc, idxf, out);
}